// Round 11
// baseline (390.625 us; speedup 1.0000x reference)
//
#include <hip/hip_runtime.h>
#include <math.h>

#define TB 32
#define TT 1000
#define TD 512
#define TU 5
#define TT1 1001

// d_out float offsets (return order: acoustic, token_num, alphas_t, cif_peak, token_num2)
#define OFF_ACC  0
#define OFF_TOKN 16400384
#define OFF_ALPH 16400416
#define OFF_PEAK 16432448
#define OFF_TOK2 16464480

typedef _Float16 half8 __attribute__((ext_vector_type(8)));
typedef _Float16 half2t __attribute__((ext_vector_type(2)));
typedef float float4t __attribute__((ext_vector_type(4)));

// global_load_lds: 16B per lane, LDS dest = wave-uniform base + lane*16 (m97 pattern)
typedef __attribute__((address_space(3))) uint32_t lds_u32_t;
typedef __attribute__((address_space(1))) const uint32_t g_u32_t;
#define GLOAD_LDS(gp, lp) __builtin_amdgcn_global_load_lds((g_u32_t*)(gp), (lds_u32_t*)(lp), 16, 0, 0)

#define BSTR 72    // halves per B row: [h x32][l x32][pad x8]
#define ASTR 200   // halves per A row: 3 taps x ([h x32][l x32]) + pad 8
#define EROWS 1032 // encs rows per (b,ic): 1 front pad + 1000 + 31 back pad

// kconvMD LDS: sB 258*72 + sA 256*200 halves = 18576 + 51200 = 69776 halves = 139552 B
#define SB_HALVES 18576
#define SMEM_BYTES ((SB_HALVES + 256 * ASTR) * 2)

// ws float-index layout (small region, both paths)
#define WS_ARAW1 0
#define WS_ARAW2 32000
#define WS_VMAT  192000
#define WS_C2    194560
#define WS_WA    194564
#define WS_WB    226596
#define WS_FIRE  258628
#define WS_NF    290660
// big region (path A only), byte offsets
// *** HAZARD (root cause of R6/R7/R9 failures): true encs size is
// *** 512*1032*144 = 76,087,296 B but cws starts at +76,059,648 — cws[0..13824)
// *** ALIASES encs bic-511 rows 840..1031. Correctness invariant: all encs
// *** writers (kpad/ksplitE) MUST complete before cws is written (ksplitW/kwv).
#define WS_ENCS_BYTES 1163264ull                      // float idx 290816
#define WS_CWS_BYTES  (WS_ENCS_BYTES + 76059648ull)
#define WS_NEED_BYTES (WS_CWS_BYTES + 3276800ull)     // cws  = 16*16*32*200*2 B

// ---------------- standalone prep kernels (path B fallback) ----------------
__global__ __launch_bounds__(256) void kzero(float* araw1, float* araw2, float* tok2) {
    int idx = blockIdx.x * 256 + threadIdx.x;
    int stride = gridDim.x * 256;
    for (int i = idx; i < TB * TT; i += stride) araw1[i] = 0.f;
    for (int i = idx; i < TB * TT * TU; i += stride) araw2[i] = 0.f;
    if (idx < TB) tok2[idx] = 0.f;
}

__global__ __launch_bounds__(256) void kc2(const float* __restrict__ up_b, const float* __restrict__ w2,
                                           const float* __restrict__ b2, float* __restrict__ c2out) {
    int tid = threadIdx.x;
    float p = 0.f;
    for (int o = tid; o < TD; o += 256) p += up_b[o] * w2[o];
#pragma unroll
    for (int m = 1; m < 64; m <<= 1) p += __shfl_xor(p, m);
    __shared__ float wsum[4];
    if ((tid & 63) == 0) wsum[tid >> 6] = p;
    __syncthreads();
    if (tid == 0) c2out[0] = b2[0] + wsum[0] + wsum[1] + wsum[2] + wsum[3];
}

__global__ __launch_bounds__(64) void kv(const float* __restrict__ up_w, const float* __restrict__ w2,
                                         float* __restrict__ vmat) {
    int i = blockIdx.x, lane = threadIdx.x;
    float s0 = 0, s1 = 0, s2 = 0, s3 = 0, s4 = 0;
    for (int o = lane; o < TD; o += 64) {
        float w = w2[o];
        const float* p = up_w + (size_t)i * (TD * TU) + o * TU;
        s0 += p[0] * w; s1 += p[1] * w; s2 += p[2] * w; s3 += p[3] * w; s4 += p[4] * w;
    }
#pragma unroll
    for (int m = 1; m < 64; m <<= 1) {
        s0 += __shfl_xor(s0, m); s1 += __shfl_xor(s1, m); s2 += __shfl_xor(s2, m);
        s3 += __shfl_xor(s3, m); s4 += __shfl_xor(s4, m);
    }
    if (lane == 0) {
        float* d = vmat + i * TU;
        d[0] = s0; d[1] = s1; d[2] = s2; d[3] = s3; d[4] = s4;
    }
}

// ---------------- fused zero-fill: kzero + kpad (path A) ----------------
#define FILL_BLOCKS (256 + 1024)
__global__ __launch_bounds__(256) void kfill(float* araw1, float* araw2, float* tok2,
                                             _Float16* encs) {
    int bid = blockIdx.x, tid = threadIdx.x;
    if (bid < 256) {  // kzero arm
        int idx = bid * 256 + tid;
        int stride = 256 * 256;
        for (int i = idx; i < TB * TT; i += stride) araw1[i] = 0.f;
        for (int i = idx; i < TB * TT * TU; i += stride) araw2[i] = 0.f;
        if (idx < TB) tok2[idx] = 0.f;
    } else {  // kpad arm: zero encs pad rows (row 0 and rows 1001..1031 per bic)
        uint32_t* p = (uint32_t*)encs;
        int idx = (bid - 256) * 256 + tid;
        int stride = 1024 * 256;
        const int total = 512 * 32 * 36;  // bic x padrow x u32-per-row
        for (int u = idx; u < total; u += stride) {
            int bic = u / (32 * 36);
            int r = (u / 36) % 32;
            int w = u % 36;
            int row = (r == 0) ? 0 : 1000 + r;
            p[((size_t)bic * EROWS + row) * 36 + w] = 0u;
        }
    }
}

// ---------------- fused weight prep: kv + ksplitW (path A) ----------------
// MUST launch after kfill AND ksplitE (see WS_CWS_BYTES hazard note).
#define WV_BLOCKS (TD + TD)
__global__ __launch_bounds__(64) void kwv(const float* __restrict__ up_w, const float* __restrict__ w2,
                                          const float* __restrict__ cw,
                                          float* __restrict__ vmat, _Float16* __restrict__ cws) {
    int bid = blockIdx.x, lane = threadIdx.x;
    if (bid < TD) {  // kv arm
        int i = bid;
        float s0 = 0, s1 = 0, s2 = 0, s3 = 0, s4 = 0;
        for (int o = lane; o < TD; o += 64) {
            float w = w2[o];
            const float* p = up_w + (size_t)i * (TD * TU) + o * TU;
            s0 += p[0] * w; s1 += p[1] * w; s2 += p[2] * w; s3 += p[3] * w; s4 += p[4] * w;
        }
#pragma unroll
        for (int m = 1; m < 64; m <<= 1) {
            s0 += __shfl_xor(s0, m); s1 += __shfl_xor(s1, m); s2 += __shfl_xor(s2, m);
            s3 += __shfl_xor(s3, m); s4 += __shfl_xor(s4, m);
        }
        if (lane == 0) {
            float* d = vmat + i * TU;
            d[0] = s0; d[1] = s1; d[2] = s2; d[3] = s3; d[4] = s4;
        }
    } else {  // ksplitW arm
        int o = bid - TD;
        for (int u = lane; u < 16 * 32 * 3; u += 64) {
            int tap = u % 3, pos = (u / 3) % 32, ic = u / 96;
            float x = cw[((size_t)o * TD + ic * 32 + pos) * 3 + tap];
            _Float16 h = (_Float16)x;
            _Float16 l = (_Float16)(x - (float)h);
            size_t base = (((size_t)(o >> 5) * 16 + ic) * 32 + (o & 31)) * ASTR + tap * 64;
            cws[base + pos] = h;
            cws[base + 32 + pos] = l;
        }
    }
}

// ---------------- path A prep: split enc -> encs halves (h/l), BSTR layout ----------------
__global__ __launch_bounds__(256) void ksplitE(const float* __restrict__ enc, _Float16* __restrict__ encs) {
    int t = blockIdx.x, b = blockIdx.y, tid = threadIdx.x;
    int c = tid * 2;
    const float2 x2 = *(const float2*)&enc[((size_t)b * TT + t) * TD + c];
    float x0 = x2.x, x1 = x2.y;
    _Float16 h0 = (_Float16)x0, h1 = (_Float16)x1;
    _Float16 l0 = (_Float16)(x0 - (float)h0), l1 = (_Float16)(x1 - (float)h1);
    int ic = c >> 5, pos = c & 31;
    size_t base = ((size_t)(b * 16 + ic) * EROWS + 1 + t) * BSTR + pos;
    half2t hh; hh[0] = h0; hh[1] = h1;
    half2t ll; ll[0] = l0; ll[1] = l1;
    *(half2t*)&encs[base] = hh;
    *(half2t*)&encs[base + 32] = ll;
}

// ---------------- conv1d via fp16x3-split MFMA, DMA-staged (path A) ----------------
// R11: block 256t x 256o, 8 waves (512 thr, launch_bounds(512,2) -> <=256 VGPR, 2 waves/SIMD),
// 139.5 KB dynamic LDS, grid (4,2,32) = 1 block/CU single turn.
// Rationale (R10 post-mortem): conv at 152 us vs 75 us max-pipe floor; B-tile re-staged by
// 8 oc-blocks = 608 MB of L3 traffic (~6.8 TB/s). 256-o block halves B re-reads (8x -> 2x)
// and cuts LDS reads 25% (wave Ot=8: 72 reads per 288 MFMA vs 48/144).
// Per-o FP chains (16 ic x 3 tap x {hh,hl,lh}) identical to R10 -> per-wave outputs
// bit-identical; only atomic partial grouping changes (4x128-o vs 8x64-o sums, ~1 ulp).
__global__ __launch_bounds__(512, 2) void kconvMD(const _Float16* __restrict__ encs,
                                                  const _Float16* __restrict__ cws,
                                                  const float* __restrict__ cb, const float* __restrict__ w1,
                                                  const float* __restrict__ vmat,
                                                  float* __restrict__ araw1, float* __restrict__ araw2) {
    extern __shared__ _Float16 smem[];
    _Float16* sB = smem;               // 258 rows x BSTR
    _Float16* sA = smem + SB_HALVES;   // 256 rows x ASTR (8 groups of 32 o)

    const int tid = threadIdx.x;
    const int t0 = blockIdx.x * 256;
    const int oc8 = blockIdx.y * 8;    // eight 32-o groups per block
    const int b = blockIdx.z;
    const int o0 = blockIdx.y * 256;
    const int wv = tid >> 6, lane = tid & 63;
    const int wt = wv & 3;             // t-quarter (64 t)
    const int wo = wv >> 2;            // o-half (128 o)
    const int q = lane >> 4, l15 = lane & 15;

    float4t acc[8][4];
#pragma unroll
    for (int i = 0; i < 8; ++i)
#pragma unroll
        for (int j = 0; j < 4; ++j) acc[i][j] = (float4t){0.f, 0.f, 0.f, 0.f};

#pragma unroll 1
    for (int ic = 0; ic < 16; ++ic) {
        __syncthreads();
        // B tile first (L3-sourced, longer latency): 258 rows x 144 B contiguous
        const _Float16* gB = encs + ((size_t)(b * 16 + ic) * EROWS + t0) * BSTR;
        for (int c = tid; c < 2322; c += 512) GLOAD_LDS(gB + c * 8, &sB[c * 8]);
        // A tile: eight 32-o groups, each 32 rows x 400 B contiguous (L2-hot: cws is 3.3 MB)
#pragma unroll
        for (int g = 0; g < 8; ++g) {
            const _Float16* gA = cws + ((size_t)((oc8 + g) * 16 + ic) * 32) * ASTR;
            for (int c = tid; c < 800; c += 512) GLOAD_LDS(gA + c * 8, &sA[g * 6400 + c * 8]);
        }
        __syncthreads();
        // ---- MFMA: 3 taps x 8 ot x (3 products x 4 tt, product-major) ----
#pragma unroll
        for (int tap = 0; tap < 3; ++tap) {
            half8 Bh[4], Bl[4];
#pragma unroll
            for (int tt = 0; tt < 4; ++tt) {
                int s = wt * 64 + tt * 16 + l15 + tap;
                Bh[tt] = *(const half8*)&sB[s * BSTR + q * 8];
                Bl[tt] = *(const half8*)&sB[s * BSTR + 32 + q * 8];
            }
#pragma unroll
            for (int ot = 0; ot < 8; ++ot) {
                const int orow = wo * 128 + ot * 16 + l15;
                half8 Ah = *(const half8*)&sA[orow * ASTR + tap * 64 + q * 8];
                half8 Al = *(const half8*)&sA[orow * ASTR + tap * 64 + 32 + q * 8];
#pragma unroll
                for (int tt = 0; tt < 4; ++tt)
                    acc[ot][tt] = __builtin_amdgcn_mfma_f32_16x16x32_f16(Ah, Bh[tt], acc[ot][tt], 0, 0, 0);
#pragma unroll
                for (int tt = 0; tt < 4; ++tt)
                    acc[ot][tt] = __builtin_amdgcn_mfma_f32_16x16x32_f16(Ah, Bl[tt], acc[ot][tt], 0, 0, 0);
#pragma unroll
                for (int tt = 0; tt < 4; ++tt)
                    acc[ot][tt] = __builtin_amdgcn_mfma_f32_16x16x32_f16(Al, Bh[tt], acc[ot][tt], 0, 0, 0);
            }
        }
    }

    // ---- epilogue: r=relu(conv+cb); 6 dots over this wave's 128 o; quad reduce; atomics ----
#pragma unroll
    for (int tt = 0; tt < 4; ++tt) {
        int t = t0 + wt * 64 + tt * 16 + l15;
        float s1 = 0.f, sa = 0.f, sb = 0.f, sc = 0.f, sd = 0.f, se = 0.f;
#pragma unroll
        for (int ot = 0; ot < 8; ++ot) {
#pragma unroll
            for (int r = 0; r < 4; ++r) {
                int o = o0 + wo * 128 + ot * 16 + q * 4 + r;
                float rv = fmaxf(acc[ot][tt][r] + cb[o], 0.f);
                s1 = fmaf(w1[o], rv, s1);
                const float* vp = &vmat[o * 5];
                sa = fmaf(vp[0], rv, sa); sb = fmaf(vp[1], rv, sb);
                sc = fmaf(vp[2], rv, sc); sd = fmaf(vp[3], rv, sd);
                se = fmaf(vp[4], rv, se);
            }
        }
        s1 += __shfl_xor(s1, 16); sa += __shfl_xor(sa, 16); sb += __shfl_xor(sb, 16);
        sc += __shfl_xor(sc, 16); sd += __shfl_xor(sd, 16); se += __shfl_xor(se, 16);
        s1 += __shfl_xor(s1, 32); sa += __shfl_xor(sa, 32); sb += __shfl_xor(sb, 32);
        sc += __shfl_xor(sc, 32); sd += __shfl_xor(sd, 32); se += __shfl_xor(se, 32);
        if (q == 0 && t < TT) {
            atomicAdd(&araw1[b * TT + t], s1);
            float* p2 = &araw2[(b * TT + t) * 5];
            atomicAdd(p2 + 0, sa); atomicAdd(p2 + 1, sb); atomicAdd(p2 + 2, sc);
            atomicAdd(p2 + 3, sd); atomicAdd(p2 + 4, se);
        }
    }
}

// ---------------- conv1d fallback (round-5 kernel, path B) ----------------
__global__ __launch_bounds__(256, 3) void kconvM(const float* __restrict__ enc, const float* __restrict__ cw,
                                                 const float* __restrict__ cb, const float* __restrict__ w1,
                                                 const float* __restrict__ vmat,
                                                 float* __restrict__ araw1, float* __restrict__ araw2) {
    __shared__ _Float16 sB[258 * BSTR];
    __shared__ _Float16 sA[32 * ASTR];

    const int tid = threadIdx.x;
    const int t0 = blockIdx.x * 256;
    const int o0 = blockIdx.y * 32;
    const int b = blockIdx.z;
    const int wv = tid >> 6, lane = tid & 63;
    const int q = lane >> 4, l15 = lane & 15;

    float4t acc[2][4];
#pragma unroll
    for (int i = 0; i < 2; ++i)
#pragma unroll
        for (int j = 0; j < 4; ++j) acc[i][j] = (float4t){0.f, 0.f, 0.f, 0.f};

    for (int i0 = 0; i0 < TD; i0 += 32) {
        __syncthreads();
        for (int u = tid; u < 258 * 16; u += 256) {
            int s = u >> 4, ii2 = (u & 15) << 1;
            int t = t0 - 1 + s;
            float x0 = 0.f, x1 = 0.f;
            if (t >= 0 && t < TT) {
                const float* p = &enc[((size_t)b * TT + t) * TD + i0 + ii2];
                x0 = p[0]; x1 = p[1];
            }
            _Float16 h0 = (_Float16)x0, h1 = (_Float16)x1;
            _Float16 l0 = (_Float16)(x0 - (float)h0), l1 = (_Float16)(x1 - (float)h1);
            half2t hh; hh[0] = h0; hh[1] = h1;
            half2t ll; ll[0] = l0; ll[1] = l1;
            *(half2t*)&sB[s * BSTR + ii2] = hh;
            *(half2t*)&sB[s * BSTR + 32 + ii2] = ll;
        }
        for (int u = tid; u < 32 * 16; u += 256) {
            int o = u >> 4, ii2 = (u & 15) << 1;
            const float* p = &cw[((size_t)(o0 + o) * TD + i0 + ii2) * 3];
#pragma unroll
            for (int k = 0; k < 3; ++k) {
                float x0 = p[k], x1 = p[3 + k];
                _Float16 h0 = (_Float16)x0, h1 = (_Float16)x1;
                _Float16 l0 = (_Float16)(x0 - (float)h0), l1 = (_Float16)(x1 - (float)h1);
                half2t hh; hh[0] = h0; hh[1] = h1;
                half2t ll; ll[0] = l0; ll[1] = l1;
                *(half2t*)&sA[o * ASTR + k * 64 + ii2] = hh;
                *(half2t*)&sA[o * ASTR + k * 64 + 32 + ii2] = ll;
            }
        }
        __syncthreads();
#pragma unroll
        for (int tap = 0; tap < 3; ++tap) {
            half8 Bh[4], Bl[4];
#pragma unroll
            for (int tt = 0; tt < 4; ++tt) {
                int s = wv * 64 + tt * 16 + l15 + tap;
                Bh[tt] = *(const half8*)&sB[s * BSTR + q * 8];
                Bl[tt] = *(const half8*)&sB[s * BSTR + 32 + q * 8];
            }
#pragma unroll
            for (int ot = 0; ot < 2; ++ot) {
                const int orow = ot * 16 + l15;
                half8 Ah = *(const half8*)&sA[orow * ASTR + tap * 64 + q * 8];
                half8 Al = *(const half8*)&sA[orow * ASTR + tap * 64 + 32 + q * 8];
#pragma unroll
                for (int tt = 0; tt < 4; ++tt) {
                    acc[ot][tt] = __builtin_amdgcn_mfma_f32_16x16x32_f16(Ah, Bh[tt], acc[ot][tt], 0, 0, 0);
                    acc[ot][tt] = __builtin_amdgcn_mfma_f32_16x16x32_f16(Ah, Bl[tt], acc[ot][tt], 0, 0, 0);
                    acc[ot][tt] = __builtin_amdgcn_mfma_f32_16x16x32_f16(Al, Bh[tt], acc[ot][tt], 0, 0, 0);
                }
            }
        }
    }

#pragma unroll
    for (int tt = 0; tt < 4; ++tt) {
        int t = t0 + wv * 64 + tt * 16 + l15;
        float s1 = 0.f, sa = 0.f, sb = 0.f, sc = 0.f, sd = 0.f, se = 0.f;
#pragma unroll
        for (int ot = 0; ot < 2; ++ot) {
#pragma unroll
            for (int r = 0; r < 4; ++r) {
                int o = o0 + ot * 16 + q * 4 + r;
                float rv = fmaxf(acc[ot][tt][r] + cb[o], 0.f);
                s1 = fmaf(w1[o], rv, s1);
                const float* vp = &vmat[o * 5];
                sa = fmaf(vp[0], rv, sa); sb = fmaf(vp[1], rv, sb);
                sc = fmaf(vp[2], rv, sc); sd = fmaf(vp[3], rv, sd);
                se = fmaf(vp[4], rv, se);
            }
        }
        s1 += __shfl_xor(s1, 16); sa += __shfl_xor(sa, 16); sb += __shfl_xor(sb, 16);
        sc += __shfl_xor(sc, 16); sd += __shfl_xor(sd, 16); se += __shfl_xor(se, 16);
        s1 += __shfl_xor(s1, 32); sa += __shfl_xor(sa, 32); sb += __shfl_xor(sb, 32);
        sc += __shfl_xor(sc, 32); sd += __shfl_xor(sd, 32); se += __shfl_xor(se, 32);
        if (q == 0 && t < TT) {
            atomicAdd(&araw1[b * TT + t], s1);
            float* p2 = &araw2[(b * TT + t) * 5];
            atomicAdd(p2 + 0, sa); atomicAdd(p2 + 1, sb); atomicAdd(p2 + 2, sc);
            atomicAdd(p2 + 3, sd); atomicAdd(p2 + 4, se);
        }
    }
}

// ---------------- fused alphas + sequential CIF scan ----------------
#define STEP(j, aj) { \
    float dist = 1.f - integ; \
    integ += (aj); \
    sp[tq + (j)] = integ; \
    bool fire = integ >= 1.f; \
    float cur = fire ? dist : (aj); \
    swa[tq + (j)] = cur; \
    swb[tq + (j)] = fire ? ((aj) - cur) : 0.f; \
    if (fire) { sf[F++] = tq + (j); integ -= 1.f; } \
    Ssum += (aj); }

__global__ __launch_bounds__(64) void kscan(const float* __restrict__ araw1, const float* __restrict__ araw2,
                                            const float* __restrict__ mask, const float* __restrict__ b1,
                                            const float* __restrict__ c2,
                                            float* __restrict__ alphas_t,
                                            float* __restrict__ cif_peak, float* __restrict__ token_num,
                                            float* __restrict__ tok2,
                                            float* __restrict__ wA, float* __restrict__ wB,
                                            int* __restrict__ fire_time, int* __restrict__ n_fires) {
    __shared__ float sa[TT1 + 7], sp[TT1], swa[TT1], swb[TT1];
    __shared__ int sf[TT1];
    __shared__ int sFs;
    int b = blockIdx.x, lane = threadIdx.x;

    // ---- phase 1: alphas (old kalpha, same scalar expressions) ----
    const float cc = c2[0];
    const float b1v = b1[0];
    float sum5 = 0.f;
    for (int t = lane; t < TT1 + 7; t += 64) {
        float av = 0.f;
        if (t < TT) {
            float mk = mask[b * TT + t];
            float a1 = araw1[b * TT + t] + b1v;
            float alpha = mk / (1.f + expf(-a1));
            float mprev = (t == 0) ? 1.f : mask[b * TT + t - 1];
            float tail = (mprev - mk) * 0.45f;
            av = alpha + tail;
            float x0 = araw2[(b * TT + t) * 5 + 0] + cc;
            float x1 = araw2[(b * TT + t) * 5 + 1] + cc;
            float x2 = araw2[(b * TT + t) * 5 + 2] + cc;
            float x3 = araw2[(b * TT + t) * 5 + 3] + cc;
            float x4 = araw2[(b * TT + t) * 5 + 4] + cc;
            sum5 += mk / (1.f + expf(-x0)) + mk / (1.f + expf(-x1)) + mk / (1.f + expf(-x2))
                  + mk / (1.f + expf(-x3)) + mk / (1.f + expf(-x4));
        } else if (t == TT) {
            av = mask[b * TT + TT - 1] * 0.45f;
        }
        sa[t] = (t < TT1) ? av : 0.f;
        if (t < TT1) alphas_t[b * TT1 + t] = av;
    }
#pragma unroll
    for (int m = 1; m < 64; m <<= 1) sum5 += __shfl_xor(sum5, m);
    if (lane == 0) tok2[b] = sum5;
    __syncthreads();

    // ---- phase 2: serial scan (unchanged) ----
    if (lane == 0) {
        float integ = 0.f, Ssum = 0.f;
        int F = 0;
        for (int tq = 0; tq < TT1 - 1; tq += 8) {  // 125 full chunks of 8 -> t=0..999
            float a0 = sa[tq], a1 = sa[tq + 1], a2 = sa[tq + 2], a3 = sa[tq + 3];
            float a4 = sa[tq + 4], a5 = sa[tq + 5], a6 = sa[tq + 6], a7 = sa[tq + 7];
            STEP(0, a0) STEP(1, a1) STEP(2, a2) STEP(3, a3)
            STEP(4, a4) STEP(5, a5) STEP(6, a6) STEP(7, a7)
        }
        { int tq = TT1 - 1; float a0 = sa[tq]; STEP(0, a0) }  // t = 1000
        token_num[b] = floorf(Ssum);
        n_fires[b] = F;
        sFs = F;
    }
    __syncthreads();
    int F = sFs;
    for (int t = lane; t < TT1; t += 64) {
        cif_peak[b * TT1 + t] = sp[t];
        wA[b * TT1 + t] = swa[t];
        wB[b * TT1 + t] = swb[t];
        if (t < F) fire_time[b * TT1 + t] = sf[t];
    }
}

// ---------------- gather: acoustic[b,k,:] = segmented weighted sum of encoder rows ----------------
__global__ __launch_bounds__(128) void kgather(const float* __restrict__ enc,
                                               const float* __restrict__ wA, const float* __restrict__ wB,
                                               const int* __restrict__ fire_time, const int* __restrict__ n_fires,
                                               float* __restrict__ acoustic) {
    int k = blockIdx.x, b = blockIdx.y;
    int d4 = threadIdx.x;
    float ox = 0.f, oy = 0.f, oz = 0.f, ow = 0.f;
    int nf = n_fires[b];
    if (k < nf) {
        int end = fire_time[b * TT1 + k];
        int start = (k > 0) ? fire_time[b * TT1 + k - 1] : 0;
        for (int t = start; t <= end; ++t) {
            if (t >= TT) continue;
            float w = (k > 0 && t == start) ? wB[b * TT1 + t] : wA[b * TT1 + t];
            float4 h = ((const float4*)(enc + ((size_t)b * TT + t) * TD))[d4];
            ox += w * h.x; oy += w * h.y; oz += w * h.z; ow += w * h.w;
        }
    }
    float4 o4; o4.x = ox; o4.y = oy; o4.z = oz; o4.w = ow;
    ((float4*)(acoustic + ((size_t)b * TT1 + k) * TD))[d4] = o4;
}

extern "C" void kernel_launch(void* const* d_in, const int* in_sizes, int n_in,
                              void* d_out, int out_size, void* d_ws, size_t ws_size,
                              hipStream_t stream) {
    (void)in_sizes; (void)n_in; (void)out_size;
    const float* enc = (const float*)d_in[0];
    const float* mask = (const float*)d_in[1];
    const float* cw = (const float*)d_in[2];
    const float* cb = (const float*)d_in[3];
    const float* upw = (const float*)d_in[4];
    const float* upb = (const float*)d_in[5];
    const float* w1 = (const float*)d_in[6];
    const float* b1 = (const float*)d_in[7];
    const float* w2 = (const float*)d_in[8];
    const float* b2 = (const float*)d_in[9];

    float* out = (float*)d_out;
    float* acoustic = out + OFF_ACC;
    float* token_num = out + OFF_TOKN;
    float* alphas_t = out + OFF_ALPH;
    float* cif_peak = out + OFF_PEAK;
    float* tok2 = out + OFF_TOK2;

    float* ws = (float*)d_ws;
    float* araw1 = ws + WS_ARAW1;
    float* araw2 = ws + WS_ARAW2;
    float* vmat = ws + WS_VMAT;
    float* c2 = ws + WS_C2;
    float* wA = ws + WS_WA;
    float* wB = ws + WS_WB;
    int* fire_time = (int*)(ws + WS_FIRE);
    int* n_fires = (int*)(ws + WS_NF);
    _Float16* encs = (_Float16*)((char*)d_ws + WS_ENCS_BYTES);
    _Float16* cws = (_Float16*)((char*)d_ws + WS_CWS_BYTES);

    const bool bigws = (ws_size >= WS_NEED_BYTES);  // constant across calls -> graph-safe

    // allow >64KB dynamic LDS for kconvMD (host-side, idempotent, graph-capture-safe)
    static bool attr_set = false;
    if (!attr_set) {
        hipFuncSetAttribute(reinterpret_cast<const void*>(&kconvMD),
                            hipFuncAttributeMaxDynamicSharedMemorySize, SMEM_BYTES);
        attr_set = true;
    }

    if (bigws) {
        // ORDER MATTERS: all encs writers (kfill's kpad arm, ksplitE) must precede
        // kwv (cws writer) because cws aliases the encs tail — see WS_CWS_BYTES note.
        hipLaunchKernelGGL(kfill, dim3(FILL_BLOCKS), dim3(256), 0, stream, araw1, araw2, tok2, encs);
        hipLaunchKernelGGL(ksplitE, dim3(TT, TB), dim3(256), 0, stream, enc, encs);
        hipLaunchKernelGGL(kc2, dim3(1), dim3(256), 0, stream, upb, w2, b2, c2);
        hipLaunchKernelGGL(kwv, dim3(WV_BLOCKS), dim3(64), 0, stream, upw, w2, cw, vmat, cws);
        hipLaunchKernelGGL(kconvMD, dim3(4, 2, TB), dim3(512), SMEM_BYTES, stream,
                           encs, cws, cb, w1, vmat, araw1, araw2);
    } else {
        hipLaunchKernelGGL(kzero, dim3(256), dim3(256), 0, stream, araw1, araw2, tok2);
        hipLaunchKernelGGL(kc2, dim3(1), dim3(256), 0, stream, upb, w2, b2, c2);
        hipLaunchKernelGGL(kv, dim3(TD), dim3(64), 0, stream, upw, w2, vmat);
        hipLaunchKernelGGL(kconvM, dim3(4, 16, TB), dim3(256), 0, stream, enc, cw, cb, w1, vmat, araw1, araw2);
    }
    hipLaunchKernelGGL(kscan, dim3(TB), dim3(64), 0, stream, araw1, araw2, mask, b1, c2,
                       alphas_t, cif_peak, token_num, tok2, wA, wB, fire_time, n_fires);
    hipLaunchKernelGGL(kgather, dim3(TT1, TB), dim3(128), 0, stream, enc, wA, wB, fire_time, n_fires, acoustic);
}

// Round 12
// 389.473 us; speedup vs baseline: 1.0030x; 1.0030x over previous
//
#include <hip/hip_runtime.h>
#include <math.h>

#define TB 32
#define TT 1000
#define TD 512
#define TU 5
#define TT1 1001

// d_out float offsets (return order: acoustic, token_num, alphas_t, cif_peak, token_num2)
#define OFF_ACC  0
#define OFF_TOKN 16400384
#define OFF_ALPH 16400416
#define OFF_PEAK 16432448
#define OFF_TOK2 16464480

typedef _Float16 half8 __attribute__((ext_vector_type(8)));
typedef _Float16 half2t __attribute__((ext_vector_type(2)));
typedef _Float16 half4t __attribute__((ext_vector_type(4)));
typedef float float4t __attribute__((ext_vector_type(4)));

// global_load_lds: 16B per lane, LDS dest = wave-uniform base + lane*16 (m97 pattern)
typedef __attribute__((address_space(3))) uint32_t lds_u32_t;
typedef __attribute__((address_space(1))) const uint32_t g_u32_t;
#define GLOAD_LDS(gp, lp) __builtin_amdgcn_global_load_lds((g_u32_t*)(gp), (lds_u32_t*)(lp), 16, 0, 0)

#define BSTR 72    // halves per B row: [h x32][l x32][pad x8]
#define ASTR 200   // halves per A row: 3 taps x ([h x32][l x32]) + pad 8
#define EROWS 1032 // encs rows per (b,ic): 1 front pad + 1000 + 31 back pad

// ws float-index layout (small region, both paths)
#define WS_ARAW1 0
#define WS_ARAW2 32000
#define WS_VMAT  192000
#define WS_C2    194560
#define WS_WA    194564
#define WS_WB    226596
#define WS_FIRE  258628
#define WS_NF    290660
// big region (path A only), byte offsets
// *** HAZARD (root cause of R6/R7/R9 failures): true encs size is
// *** 512*1032*144 = 76,087,296 B but cws starts at +76,059,648 — cws[0..13824)
// *** ALIASES encs bic-511 rows 840..1031. Correctness invariant: all encs
// *** writers (kpad/ksplitE) MUST complete before cws is written (ksplitW/kwv).
#define WS_ENCS_BYTES 1163264ull                      // float idx 290816
#define WS_CWS_BYTES  (WS_ENCS_BYTES + 76059648ull)
#define WS_NEED_BYTES (WS_CWS_BYTES + 3276800ull)     // cws  = 16*16*32*200*2 B

// ---------------- standalone prep kernels (path B fallback) ----------------
__global__ __launch_bounds__(256) void kzero(float* araw1, float* araw2, float* tok2) {
    int idx = blockIdx.x * 256 + threadIdx.x;
    int stride = gridDim.x * 256;
    for (int i = idx; i < TB * TT; i += stride) araw1[i] = 0.f;
    for (int i = idx; i < TB * TT * TU; i += stride) araw2[i] = 0.f;
    if (idx < TB) tok2[idx] = 0.f;
}

__global__ __launch_bounds__(256) void kc2(const float* __restrict__ up_b, const float* __restrict__ w2,
                                           const float* __restrict__ b2, float* __restrict__ c2out) {
    int tid = threadIdx.x;
    float p = 0.f;
    for (int o = tid; o < TD; o += 256) p += up_b[o] * w2[o];
#pragma unroll
    for (int m = 1; m < 64; m <<= 1) p += __shfl_xor(p, m);
    __shared__ float wsum[4];
    if ((tid & 63) == 0) wsum[tid >> 6] = p;
    __syncthreads();
    if (tid == 0) c2out[0] = b2[0] + wsum[0] + wsum[1] + wsum[2] + wsum[3];
}

__global__ __launch_bounds__(64) void kv(const float* __restrict__ up_w, const float* __restrict__ w2,
                                         float* __restrict__ vmat) {
    int i = blockIdx.x, lane = threadIdx.x;
    float s0 = 0, s1 = 0, s2 = 0, s3 = 0, s4 = 0;
    for (int o = lane; o < TD; o += 64) {
        float w = w2[o];
        const float* p = up_w + (size_t)i * (TD * TU) + o * TU;
        s0 += p[0] * w; s1 += p[1] * w; s2 += p[2] * w; s3 += p[3] * w; s4 += p[4] * w;
    }
#pragma unroll
    for (int m = 1; m < 64; m <<= 1) {
        s0 += __shfl_xor(s0, m); s1 += __shfl_xor(s1, m); s2 += __shfl_xor(s2, m);
        s3 += __shfl_xor(s3, m); s4 += __shfl_xor(s4, m);
    }
    if (lane == 0) {
        float* d = vmat + i * TU;
        d[0] = s0; d[1] = s1; d[2] = s2; d[3] = s3; d[4] = s4;
    }
}

// ---------------- fused zero-fill: kzero + kpad (path A) ----------------
#define FILL_BLOCKS (256 + 1024)
__global__ __launch_bounds__(256) void kfill(float* araw1, float* araw2, float* tok2,
                                             _Float16* encs) {
    int bid = blockIdx.x, tid = threadIdx.x;
    if (bid < 256) {  // kzero arm
        int idx = bid * 256 + tid;
        int stride = 256 * 256;
        for (int i = idx; i < TB * TT; i += stride) araw1[i] = 0.f;
        for (int i = idx; i < TB * TT * TU; i += stride) araw2[i] = 0.f;
        if (idx < TB) tok2[idx] = 0.f;
    } else {  // kpad arm: zero encs pad rows (row 0 and rows 1001..1031 per bic)
        uint32_t* p = (uint32_t*)encs;
        int idx = (bid - 256) * 256 + tid;
        int stride = 1024 * 256;
        const int total = 512 * 32 * 36;  // bic x padrow x u32-per-row
        for (int u = idx; u < total; u += stride) {
            int bic = u / (32 * 36);
            int r = (u / 36) % 32;
            int w = u % 36;
            int row = (r == 0) ? 0 : 1000 + r;
            p[((size_t)bic * EROWS + row) * 36 + w] = 0u;
        }
    }
}

// ---------------- fused weight prep: kv + ksplitW + kc2 (path A) ----------------
// MUST launch after kfill AND ksplitE (see WS_CWS_BYTES hazard note).
// kc2 arm uses 64 lanes (8 terms each) vs old 256-thread version: reduction-order
// change only, c2 shifts <=1 ulp; c2 feeds smooth sigmoid paths only (no CIF fire logic).
#define WV_BLOCKS (TD + TD + 1)
__global__ __launch_bounds__(64) void kwv(const float* __restrict__ up_w, const float* __restrict__ w2,
                                          const float* __restrict__ cw,
                                          const float* __restrict__ up_b, const float* __restrict__ b2,
                                          float* __restrict__ vmat, _Float16* __restrict__ cws,
                                          float* __restrict__ c2out) {
    int bid = blockIdx.x, lane = threadIdx.x;
    if (bid < TD) {  // kv arm
        int i = bid;
        float s0 = 0, s1 = 0, s2 = 0, s3 = 0, s4 = 0;
        for (int o = lane; o < TD; o += 64) {
            float w = w2[o];
            const float* p = up_w + (size_t)i * (TD * TU) + o * TU;
            s0 += p[0] * w; s1 += p[1] * w; s2 += p[2] * w; s3 += p[3] * w; s4 += p[4] * w;
        }
#pragma unroll
        for (int m = 1; m < 64; m <<= 1) {
            s0 += __shfl_xor(s0, m); s1 += __shfl_xor(s1, m); s2 += __shfl_xor(s2, m);
            s3 += __shfl_xor(s3, m); s4 += __shfl_xor(s4, m);
        }
        if (lane == 0) {
            float* d = vmat + i * TU;
            d[0] = s0; d[1] = s1; d[2] = s2; d[3] = s3; d[4] = s4;
        }
    } else if (bid < 2 * TD) {  // ksplitW arm
        int o = bid - TD;
        for (int u = lane; u < 16 * 32 * 3; u += 64) {
            int tap = u % 3, pos = (u / 3) % 32, ic = u / 96;
            float x = cw[((size_t)o * TD + ic * 32 + pos) * 3 + tap];
            _Float16 h = (_Float16)x;
            _Float16 l = (_Float16)(x - (float)h);
            size_t base = (((size_t)(o >> 5) * 16 + ic) * 32 + (o & 31)) * ASTR + tap * 64;
            cws[base + pos] = h;
            cws[base + 32 + pos] = l;
        }
    } else {  // kc2 arm
        float p = 0.f;
        for (int o = lane; o < TD; o += 64) p += up_b[o] * w2[o];
#pragma unroll
        for (int m = 1; m < 64; m <<= 1) p += __shfl_xor(p, m);
        if (lane == 0) c2out[0] = b2[0] + p;
    }
}

// ---------------- path A prep: split enc -> encs halves (h/l), BSTR layout ----------------
// 128 threads x 4 floats (float4 load, two 8B stores). Same addresses/values as the
// proven 256x2 version — pos = c&31 is 4-aligned so the 4 halves are contiguous.
__global__ __launch_bounds__(128) void ksplitE(const float* __restrict__ enc, _Float16* __restrict__ encs) {
    int t = blockIdx.x, b = blockIdx.y, tid = threadIdx.x;
    int c = tid * 4;
    const float4 x4 = *(const float4*)&enc[((size_t)b * TT + t) * TD + c];
    _Float16 h0 = (_Float16)x4.x, h1 = (_Float16)x4.y, h2 = (_Float16)x4.z, h3 = (_Float16)x4.w;
    _Float16 l0 = (_Float16)(x4.x - (float)h0), l1 = (_Float16)(x4.y - (float)h1);
    _Float16 l2 = (_Float16)(x4.z - (float)h2), l3 = (_Float16)(x4.w - (float)h3);
    int ic = c >> 5, pos = c & 31;
    size_t base = ((size_t)(b * 16 + ic) * EROWS + 1 + t) * BSTR + pos;
    half4t hh; hh[0] = h0; hh[1] = h1; hh[2] = h2; hh[3] = h3;
    half4t ll; ll[0] = l0; ll[1] = l1; ll[2] = l2; ll[3] = l3;
    *(half4t*)&encs[base] = hh;
    *(half4t*)&encs[base + 32] = ll;
}

// ---------------- conv1d via fp16x3-split MFMA, DMA-staged (path A) ----------------
// EXACT R1/R8/R10 kernel (hardware-proven: 152.0 us, absmax 4.03125).
// Block: 64 o x 256 t, 4 waves, 2 blocks/CU (62.9 KB static LDS) = 8 waves/CU.
// Structure notes from this session's experiments:
//  - waves/CU is the binding knob: 8 beats 12 (reuse) and 4 (no cross-wave overlap).
//  - The ~77us gap above the 74.5us MFMA floor is the per-round vmcnt(0)-drain+barrier
//    serialization; dbuf escape needs 2x LDS which exceeds 160KB at any 8-wave tile.
//  - R11 (256-o, halved B re-reads, -25% LDS reads) was FLAT -> L3 BW and LDS reads
//    are not binding. Do not re-attempt traffic-reduction variants.
__global__ __launch_bounds__(256, 2) void kconvMD(const _Float16* __restrict__ encs,
                                                  const _Float16* __restrict__ cws,
                                                  const float* __restrict__ cb, const float* __restrict__ w1,
                                                  const float* __restrict__ vmat,
                                                  float* __restrict__ araw1, float* __restrict__ araw2) {
    __shared__ _Float16 sB[258 * BSTR];  // 37.1 KB; LDS row s = data t = t0-1+s
    __shared__ _Float16 sA[64 * ASTR];   // 25.6 KB (two 32-o groups)

    const int tid = threadIdx.x;
    const int t0 = blockIdx.x * 256;
    const int oc = blockIdx.y;           // 0..7, 64 outputs each
    const int b = blockIdx.z;
    const int o0 = oc * 64;
    const int wv = tid >> 6, lane = tid & 63;
    const int q = lane >> 4, l15 = lane & 15;

    float4t acc[4][4];
#pragma unroll
    for (int i = 0; i < 4; ++i)
#pragma unroll
        for (int j = 0; j < 4; ++j) acc[i][j] = (float4t){0.f, 0.f, 0.f, 0.f};

    for (int ic = 0; ic < 16; ++ic) {
        __syncthreads();
        // B tile: 258 rows x 144 B, contiguous in encs (front pad row makes t0-1 legal)
        const _Float16* gB = encs + ((size_t)(b * 16 + ic) * EROWS + t0) * BSTR;
        for (int c = tid; c < 2322; c += 256) GLOAD_LDS(gB + c * 8, &sB[c * 8]);
        // A tile: two 32-o groups, each 32 rows x 400 B contiguous
        const _Float16* gA0 = cws + ((size_t)((oc * 2 + 0) * 16 + ic) * 32) * ASTR;
        const _Float16* gA1 = cws + ((size_t)((oc * 2 + 1) * 16 + ic) * 32) * ASTR;
        for (int c = tid; c < 800; c += 256) GLOAD_LDS(gA0 + c * 8, &sA[c * 8]);
        for (int c = tid; c < 800; c += 256) GLOAD_LDS(gA1 + c * 8, &sA[6400 + c * 8]);
        __syncthreads();
        // ---- MFMA: 3 taps x 4 ot x 4 tt x 3 products ----
#pragma unroll
        for (int tap = 0; tap < 3; ++tap) {
            half8 Bh[4], Bl[4];
#pragma unroll
            for (int tt = 0; tt < 4; ++tt) {
                int s = wv * 64 + tt * 16 + l15 + tap;
                Bh[tt] = *(const half8*)&sB[s * BSTR + q * 8];
                Bl[tt] = *(const half8*)&sB[s * BSTR + 32 + q * 8];
            }
#pragma unroll
            for (int ot = 0; ot < 4; ++ot) {
                const int orow = ot * 16 + l15;
                half8 Ah = *(const half8*)&sA[orow * ASTR + tap * 64 + q * 8];
                half8 Al = *(const half8*)&sA[orow * ASTR + tap * 64 + 32 + q * 8];
#pragma unroll
                for (int tt = 0; tt < 4; ++tt) {
                    acc[ot][tt] = __builtin_amdgcn_mfma_f32_16x16x32_f16(Ah, Bh[tt], acc[ot][tt], 0, 0, 0);
                    acc[ot][tt] = __builtin_amdgcn_mfma_f32_16x16x32_f16(Ah, Bl[tt], acc[ot][tt], 0, 0, 0);
                    acc[ot][tt] = __builtin_amdgcn_mfma_f32_16x16x32_f16(Al, Bh[tt], acc[ot][tt], 0, 0, 0);
                }
            }
        }
    }

    // ---- epilogue: r=relu(conv+cb); 6 dots; quad reduce; atomics ----
#pragma unroll
    for (int tt = 0; tt < 4; ++tt) {
        int t = t0 + wv * 64 + tt * 16 + l15;
        float s1 = 0.f, sa = 0.f, sb = 0.f, sc = 0.f, sd = 0.f, se = 0.f;
#pragma unroll
        for (int ot = 0; ot < 4; ++ot) {
#pragma unroll
            for (int r = 0; r < 4; ++r) {
                int o = o0 + ot * 16 + q * 4 + r;
                float rv = fmaxf(acc[ot][tt][r] + cb[o], 0.f);
                s1 = fmaf(w1[o], rv, s1);
                const float* vp = &vmat[o * 5];
                sa = fmaf(vp[0], rv, sa); sb = fmaf(vp[1], rv, sb);
                sc = fmaf(vp[2], rv, sc); sd = fmaf(vp[3], rv, sd);
                se = fmaf(vp[4], rv, se);
            }
        }
        s1 += __shfl_xor(s1, 16); sa += __shfl_xor(sa, 16); sb += __shfl_xor(sb, 16);
        sc += __shfl_xor(sc, 16); sd += __shfl_xor(sd, 16); se += __shfl_xor(se, 16);
        s1 += __shfl_xor(s1, 32); sa += __shfl_xor(sa, 32); sb += __shfl_xor(sb, 32);
        sc += __shfl_xor(sc, 32); sd += __shfl_xor(sd, 32); se += __shfl_xor(se, 32);
        if (q == 0 && t < TT) {
            atomicAdd(&araw1[b * TT + t], s1);
            float* p2 = &araw2[(b * TT + t) * 5];
            atomicAdd(p2 + 0, sa); atomicAdd(p2 + 1, sb); atomicAdd(p2 + 2, sc);
            atomicAdd(p2 + 3, sd); atomicAdd(p2 + 4, se);
        }
    }
}

// ---------------- conv1d fallback (round-5 kernel, path B) ----------------
__global__ __launch_bounds__(256, 3) void kconvM(const float* __restrict__ enc, const float* __restrict__ cw,
                                                 const float* __restrict__ cb, const float* __restrict__ w1,
                                                 const float* __restrict__ vmat,
                                                 float* __restrict__ araw1, float* __restrict__ araw2) {
    __shared__ _Float16 sB[258 * BSTR];
    __shared__ _Float16 sA[32 * ASTR];

    const int tid = threadIdx.x;
    const int t0 = blockIdx.x * 256;
    const int o0 = blockIdx.y * 32;
    const int b = blockIdx.z;
    const int wv = tid >> 6, lane = tid & 63;
    const int q = lane >> 4, l15 = lane & 15;

    float4t acc[2][4];
#pragma unroll
    for (int i = 0; i < 2; ++i)
#pragma unroll
        for (int j = 0; j < 4; ++j) acc[i][j] = (float4t){0.f, 0.f, 0.f, 0.f};

    for (int i0 = 0; i0 < TD; i0 += 32) {
        __syncthreads();
        for (int u = tid; u < 258 * 16; u += 256) {
            int s = u >> 4, ii2 = (u & 15) << 1;
            int t = t0 - 1 + s;
            float x0 = 0.f, x1 = 0.f;
            if (t >= 0 && t < TT) {
                const float* p = &enc[((size_t)b * TT + t) * TD + i0 + ii2];
                x0 = p[0]; x1 = p[1];
            }
            _Float16 h0 = (_Float16)x0, h1 = (_Float16)x1;
            _Float16 l0 = (_Float16)(x0 - (float)h0), l1 = (_Float16)(x1 - (float)h1);
            half2t hh; hh[0] = h0; hh[1] = h1;
            half2t ll; ll[0] = l0; ll[1] = l1;
            *(half2t*)&sB[s * BSTR + ii2] = hh;
            *(half2t*)&sB[s * BSTR + 32 + ii2] = ll;
        }
        for (int u = tid; u < 32 * 16; u += 256) {
            int o = u >> 4, ii2 = (u & 15) << 1;
            const float* p = &cw[((size_t)(o0 + o) * TD + i0 + ii2) * 3];
#pragma unroll
            for (int k = 0; k < 3; ++k) {
                float x0 = p[k], x1 = p[3 + k];
                _Float16 h0 = (_Float16)x0, h1 = (_Float16)x1;
                _Float16 l0 = (_Float16)(x0 - (float)h0), l1 = (_Float16)(x1 - (float)h1);
                half2t hh; hh[0] = h0; hh[1] = h1;
                half2t ll; ll[0] = l0; ll[1] = l1;
                *(half2t*)&sA[o * ASTR + k * 64 + ii2] = hh;
                *(half2t*)&sA[o * ASTR + k * 64 + 32 + ii2] = ll;
            }
        }
        __syncthreads();
#pragma unroll
        for (int tap = 0; tap < 3; ++tap) {
            half8 Bh[4], Bl[4];
#pragma unroll
            for (int tt = 0; tt < 4; ++tt) {
                int s = wv * 64 + tt * 16 + l15 + tap;
                Bh[tt] = *(const half8*)&sB[s * BSTR + q * 8];
                Bl[tt] = *(const half8*)&sB[s * BSTR + 32 + q * 8];
            }
#pragma unroll
            for (int ot = 0; ot < 2; ++ot) {
                const int orow = ot * 16 + l15;
                half8 Ah = *(const half8*)&sA[orow * ASTR + tap * 64 + q * 8];
                half8 Al = *(const half8*)&sA[orow * ASTR + tap * 64 + 32 + q * 8];
#pragma unroll
                for (int tt = 0; tt < 4; ++tt) {
                    acc[ot][tt] = __builtin_amdgcn_mfma_f32_16x16x32_f16(Ah, Bh[tt], acc[ot][tt], 0, 0, 0);
                    acc[ot][tt] = __builtin_amdgcn_mfma_f32_16x16x32_f16(Ah, Bl[tt], acc[ot][tt], 0, 0, 0);
                    acc[ot][tt] = __builtin_amdgcn_mfma_f32_16x16x32_f16(Al, Bh[tt], acc[ot][tt], 0, 0, 0);
                }
            }
        }
    }

#pragma unroll
    for (int tt = 0; tt < 4; ++tt) {
        int t = t0 + wv * 64 + tt * 16 + l15;
        float s1 = 0.f, sa = 0.f, sb = 0.f, sc = 0.f, sd = 0.f, se = 0.f;
#pragma unroll
        for (int ot = 0; ot < 2; ++ot) {
#pragma unroll
            for (int r = 0; r < 4; ++r) {
                int o = o0 + ot * 16 + q * 4 + r;
                float rv = fmaxf(acc[ot][tt][r] + cb[o], 0.f);
                s1 = fmaf(w1[o], rv, s1);
                const float* vp = &vmat[o * 5];
                sa = fmaf(vp[0], rv, sa); sb = fmaf(vp[1], rv, sb);
                sc = fmaf(vp[2], rv, sc); sd = fmaf(vp[3], rv, sd);
                se = fmaf(vp[4], rv, se);
            }
        }
        s1 += __shfl_xor(s1, 16); sa += __shfl_xor(sa, 16); sb += __shfl_xor(sb, 16);
        sc += __shfl_xor(sc, 16); sd += __shfl_xor(sd, 16); se += __shfl_xor(se, 16);
        s1 += __shfl_xor(s1, 32); sa += __shfl_xor(sa, 32); sb += __shfl_xor(sb, 32);
        sc += __shfl_xor(sc, 32); sd += __shfl_xor(sd, 32); se += __shfl_xor(se, 32);
        if (q == 0 && t < TT) {
            atomicAdd(&araw1[b * TT + t], s1);
            float* p2 = &araw2[(b * TT + t) * 5];
            atomicAdd(p2 + 0, sa); atomicAdd(p2 + 1, sb); atomicAdd(p2 + 2, sc);
            atomicAdd(p2 + 3, sd); atomicAdd(p2 + 4, se);
        }
    }
}

// ---------------- fused alphas + sequential CIF scan ----------------
#define STEP(j, aj) { \
    float dist = 1.f - integ; \
    integ += (aj); \
    sp[tq + (j)] = integ; \
    bool fire = integ >= 1.f; \
    float cur = fire ? dist : (aj); \
    swa[tq + (j)] = cur; \
    swb[tq + (j)] = fire ? ((aj) - cur) : 0.f; \
    if (fire) { sf[F++] = tq + (j); integ -= 1.f; } \
    Ssum += (aj); }

__global__ __launch_bounds__(64) void kscan(const float* __restrict__ araw1, const float* __restrict__ araw2,
                                            const float* __restrict__ mask, const float* __restrict__ b1,
                                            const float* __restrict__ c2,
                                            float* __restrict__ alphas_t,
                                            float* __restrict__ cif_peak, float* __restrict__ token_num,
                                            float* __restrict__ tok2,
                                            float* __restrict__ wA, float* __restrict__ wB,
                                            int* __restrict__ fire_time, int* __restrict__ n_fires) {
    __shared__ float sa[TT1 + 7], sp[TT1], swa[TT1], swb[TT1];
    __shared__ int sf[TT1];
    __shared__ int sFs;
    int b = blockIdx.x, lane = threadIdx.x;

    // ---- phase 1: alphas (old kalpha, same scalar expressions) ----
    const float cc = c2[0];
    const float b1v = b1[0];
    float sum5 = 0.f;
    for (int t = lane; t < TT1 + 7; t += 64) {
        float av = 0.f;
        if (t < TT) {
            float mk = mask[b * TT + t];
            float a1 = araw1[b * TT + t] + b1v;
            float alpha = mk / (1.f + expf(-a1));
            float mprev = (t == 0) ? 1.f : mask[b * TT + t - 1];
            float tail = (mprev - mk) * 0.45f;
            av = alpha + tail;
            float x0 = araw2[(b * TT + t) * 5 + 0] + cc;
            float x1 = araw2[(b * TT + t) * 5 + 1] + cc;
            float x2 = araw2[(b * TT + t) * 5 + 2] + cc;
            float x3 = araw2[(b * TT + t) * 5 + 3] + cc;
            float x4 = araw2[(b * TT + t) * 5 + 4] + cc;
            sum5 += mk / (1.f + expf(-x0)) + mk / (1.f + expf(-x1)) + mk / (1.f + expf(-x2))
                  + mk / (1.f + expf(-x3)) + mk / (1.f + expf(-x4));
        } else if (t == TT) {
            av = mask[b * TT + TT - 1] * 0.45f;
        }
        sa[t] = (t < TT1) ? av : 0.f;
        if (t < TT1) alphas_t[b * TT1 + t] = av;
    }
#pragma unroll
    for (int m = 1; m < 64; m <<= 1) sum5 += __shfl_xor(sum5, m);
    if (lane == 0) tok2[b] = sum5;
    __syncthreads();

    // ---- phase 2: serial scan (unchanged) ----
    if (lane == 0) {
        float integ = 0.f, Ssum = 0.f;
        int F = 0;
        for (int tq = 0; tq < TT1 - 1; tq += 8) {  // 125 full chunks of 8 -> t=0..999
            float a0 = sa[tq], a1 = sa[tq + 1], a2 = sa[tq + 2], a3 = sa[tq + 3];
            float a4 = sa[tq + 4], a5 = sa[tq + 5], a6 = sa[tq + 6], a7 = sa[tq + 7];
            STEP(0, a0) STEP(1, a1) STEP(2, a2) STEP(3, a3)
            STEP(4, a4) STEP(5, a5) STEP(6, a6) STEP(7, a7)
        }
        { int tq = TT1 - 1; float a0 = sa[tq]; STEP(0, a0) }  // t = 1000
        token_num[b] = floorf(Ssum);
        n_fires[b] = F;
        sFs = F;
    }
    __syncthreads();
    int F = sFs;
    for (int t = lane; t < TT1; t += 64) {
        cif_peak[b * TT1 + t] = sp[t];
        wA[b * TT1 + t] = swa[t];
        wB[b * TT1 + t] = swb[t];
        if (t < F) fire_time[b * TT1 + t] = sf[t];
    }
}

// ---------------- gather: acoustic[b,k,:] = segmented weighted sum of encoder rows ----------------
__global__ __launch_bounds__(128) void kgather(const float* __restrict__ enc,
                                               const float* __restrict__ wA, const float* __restrict__ wB,
                                               const int* __restrict__ fire_time, const int* __restrict__ n_fires,
                                               float* __restrict__ acoustic) {
    int k = blockIdx.x, b = blockIdx.y;
    int d4 = threadIdx.x;
    float ox = 0.f, oy = 0.f, oz = 0.f, ow = 0.f;
    int nf = n_fires[b];
    if (k < nf) {
        int end = fire_time[b * TT1 + k];
        int start = (k > 0) ? fire_time[b * TT1 + k - 1] : 0;
        for (int t = start; t <= end; ++t) {
            if (t >= TT) continue;
            float w = (k > 0 && t == start) ? wB[b * TT1 + t] : wA[b * TT1 + t];
            float4 h = ((const float4*)(enc + ((size_t)b * TT + t) * TD))[d4];
            ox += w * h.x; oy += w * h.y; oz += w * h.z; ow += w * h.w;
        }
    }
    float4 o4; o4.x = ox; o4.y = oy; o4.z = oz; o4.w = ow;
    ((float4*)(acoustic + ((size_t)b * TT1 + k) * TD))[d4] = o4;
}

extern "C" void kernel_launch(void* const* d_in, const int* in_sizes, int n_in,
                              void* d_out, int out_size, void* d_ws, size_t ws_size,
                              hipStream_t stream) {
    (void)in_sizes; (void)n_in; (void)out_size;
    const float* enc = (const float*)d_in[0];
    const float* mask = (const float*)d_in[1];
    const float* cw = (const float*)d_in[2];
    const float* cb = (const float*)d_in[3];
    const float* upw = (const float*)d_in[4];
    const float* upb = (const float*)d_in[5];
    const float* w1 = (const float*)d_in[6];
    const float* b1 = (const float*)d_in[7];
    const float* w2 = (const float*)d_in[8];
    const float* b2 = (const float*)d_in[9];

    float* out = (float*)d_out;
    float* acoustic = out + OFF_ACC;
    float* token_num = out + OFF_TOKN;
    float* alphas_t = out + OFF_ALPH;
    float* cif_peak = out + OFF_PEAK;
    float* tok2 = out + OFF_TOK2;

    float* ws = (float*)d_ws;
    float* araw1 = ws + WS_ARAW1;
    float* araw2 = ws + WS_ARAW2;
    float* vmat = ws + WS_VMAT;
    float* c2 = ws + WS_C2;
    float* wA = ws + WS_WA;
    float* wB = ws + WS_WB;
    int* fire_time = (int*)(ws + WS_FIRE);
    int* n_fires = (int*)(ws + WS_NF);
    _Float16* encs = (_Float16*)((char*)d_ws + WS_ENCS_BYTES);
    _Float16* cws = (_Float16*)((char*)d_ws + WS_CWS_BYTES);

    const bool bigws = (ws_size >= WS_NEED_BYTES);  // constant across calls -> graph-safe

    if (bigws) {
        // ORDER MATTERS: all encs writers (kfill's kpad arm, ksplitE) must precede
        // kwv (cws writer) because cws aliases the encs tail — see WS_CWS_BYTES note.
        hipLaunchKernelGGL(kfill, dim3(FILL_BLOCKS), dim3(256), 0, stream, araw1, araw2, tok2, encs);
        hipLaunchKernelGGL(ksplitE, dim3(TT, TB), dim3(128), 0, stream, enc, encs);
        hipLaunchKernelGGL(kwv, dim3(WV_BLOCKS), dim3(64), 0, stream, upw, w2, cw, upb, b2, vmat, cws, c2);
        hipLaunchKernelGGL(kconvMD, dim3(4, 8, TB), dim3(256), 0, stream, encs, cws, cb, w1, vmat, araw1, araw2);
    } else {
        hipLaunchKernelGGL(kzero, dim3(256), dim3(256), 0, stream, araw1, araw2, tok2);
        hipLaunchKernelGGL(kc2, dim3(1), dim3(256), 0, stream, upb, w2, b2, c2);
        hipLaunchKernelGGL(kv, dim3(TD), dim3(64), 0, stream, upw, w2, vmat);
        hipLaunchKernelGGL(kconvM, dim3(4, 16, TB), dim3(256), 0, stream, enc, cw, cb, w1, vmat, araw1, araw2);
    }
    hipLaunchKernelGGL(kscan, dim3(TB), dim3(64), 0, stream, araw1, araw2, mask, b1, c2,
                       alphas_t, cif_peak, token_num, tok2, wA, wB, fire_time, n_fires);
    hipLaunchKernelGGL(kgather, dim3(TT1, TB), dim3(128), 0, stream, enc, wA, wB, fire_time, n_fires, acoustic);
}

// Round 13
// 380.718 us; speedup vs baseline: 1.0260x; 1.0230x over previous
//
#include <hip/hip_runtime.h>
#include <math.h>

#define TB 32
#define TT 1000
#define TD 512
#define TU 5
#define TT1 1001

// d_out float offsets (return order: acoustic, token_num, alphas_t, cif_peak, token_num2)
#define OFF_ACC  0
#define OFF_TOKN 16400384
#define OFF_ALPH 16400416
#define OFF_PEAK 16432448
#define OFF_TOK2 16464480

typedef _Float16 half8 __attribute__((ext_vector_type(8)));
typedef _Float16 half2t __attribute__((ext_vector_type(2)));
typedef float float4t __attribute__((ext_vector_type(4)));

// global_load_lds: 16B per lane, LDS dest = wave-uniform base + lane*16 (m97 pattern)
typedef __attribute__((address_space(3))) uint32_t lds_u32_t;
typedef __attribute__((address_space(1))) const uint32_t g_u32_t;
#define GLOAD_LDS(gp, lp) __builtin_amdgcn_global_load_lds((g_u32_t*)(gp), (lds_u32_t*)(lp), 16, 0, 0)

#define BSTR 72    // halves per B row: [h x32][l x32][pad x8]
#define ASTR 200   // halves per A row: 3 taps x ([h x32][l x32]) + pad 8
#define EROWS 1032 // encs rows per (b,ic): 1 front pad + 1000 + 31 back pad

// ws float-index layout (small region, both paths)
#define WS_ARAW1 0
#define WS_ARAW2 32000
#define WS_VMAT  192000
#define WS_C2    194560
#define WS_WA    194564
#define WS_WB    226596
#define WS_FIRE  258628
#define WS_NF    290660
// big region (path A only), byte offsets
// *** HAZARD (root cause of R6/R7/R9 failures): true encs size is
// *** 512*1032*144 = 76,087,296 B but cws starts at +76,059,648 — cws[0..13824)
// *** ALIASES encs bic-511 rows 840..1031. Correctness invariant: all encs
// *** writers (kprepA: kpad/ksplitE arms) MUST complete before cws is written (kwv).
#define WS_ENCS_BYTES 1163264ull                      // float idx 290816
#define WS_CWS_BYTES  (WS_ENCS_BYTES + 76059648ull)
#define WS_NEED_BYTES (WS_CWS_BYTES + 3276800ull)     // cws  = 16*16*32*200*2 B

// ---------------- standalone prep kernels (path B fallback) ----------------
__global__ __launch_bounds__(256) void kzero(float* araw1, float* araw2, float* tok2) {
    int idx = blockIdx.x * 256 + threadIdx.x;
    int stride = gridDim.x * 256;
    for (int i = idx; i < TB * TT; i += stride) araw1[i] = 0.f;
    for (int i = idx; i < TB * TT * TU; i += stride) araw2[i] = 0.f;
    if (idx < TB) tok2[idx] = 0.f;
}

__global__ __launch_bounds__(256) void kc2(const float* __restrict__ up_b, const float* __restrict__ w2,
                                           const float* __restrict__ b2, float* __restrict__ c2out) {
    int tid = threadIdx.x;
    float p = 0.f;
    for (int o = tid; o < TD; o += 256) p += up_b[o] * w2[o];
#pragma unroll
    for (int m = 1; m < 64; m <<= 1) p += __shfl_xor(p, m);
    __shared__ float wsum[4];
    if ((tid & 63) == 0) wsum[tid >> 6] = p;
    __syncthreads();
    if (tid == 0) c2out[0] = b2[0] + wsum[0] + wsum[1] + wsum[2] + wsum[3];
}

__global__ __launch_bounds__(64) void kv(const float* __restrict__ up_w, const float* __restrict__ w2,
                                         float* __restrict__ vmat) {
    int i = blockIdx.x, lane = threadIdx.x;
    float s0 = 0, s1 = 0, s2 = 0, s3 = 0, s4 = 0;
    for (int o = lane; o < TD; o += 64) {
        float w = w2[o];
        const float* p = up_w + (size_t)i * (TD * TU) + o * TU;
        s0 += p[0] * w; s1 += p[1] * w; s2 += p[2] * w; s3 += p[3] * w; s4 += p[4] * w;
    }
#pragma unroll
    for (int m = 1; m < 64; m <<= 1) {
        s0 += __shfl_xor(s0, m); s1 += __shfl_xor(s1, m); s2 += __shfl_xor(s2, m);
        s3 += __shfl_xor(s3, m); s4 += __shfl_xor(s4, m);
    }
    if (lane == 0) {
        float* d = vmat + i * TU;
        d[0] = s0; d[1] = s1; d[2] = s2; d[3] = s3; d[4] = s4;
    }
}

// ---------------- fused prep A: kzero + kpad + ksplitE (path A) ----------------
// All three arms write DISJOINT ranges (kpad: encs rows {0,1001..1031}; ksplitE:
// encs rows 1..1000; kzero: araw/tok2) -> no intra-kernel ordering needed.
// Arms byte-identical to the hardware-proven standalones (R10).
#define PREPA_BLOCKS (256 + 1024 + 32000)
__global__ __launch_bounds__(256) void kprepA(const float* __restrict__ enc,
                                              float* araw1, float* araw2, float* tok2,
                                              _Float16* encs) {
    int bid = blockIdx.x, tid = threadIdx.x;
    if (bid < 256) {  // kzero arm
        int idx = bid * 256 + tid;
        int stride = 256 * 256;
        for (int i = idx; i < TB * TT; i += stride) araw1[i] = 0.f;
        for (int i = idx; i < TB * TT * TU; i += stride) araw2[i] = 0.f;
        if (idx < TB) tok2[idx] = 0.f;
    } else if (bid < 1280) {  // kpad arm: zero encs pad rows (row 0 and 1001..1031 per bic)
        uint32_t* p = (uint32_t*)encs;
        int idx = (bid - 256) * 256 + tid;
        int stride = 1024 * 256;
        const int total = 512 * 32 * 36;  // bic x padrow x u32-per-row
        for (int u = idx; u < total; u += stride) {
            int bic = u / (32 * 36);
            int r = (u / 36) % 32;
            int w = u % 36;
            int row = (r == 0) ? 0 : 1000 + r;
            p[((size_t)bic * EROWS + row) * 36 + w] = 0u;
        }
    } else {  // ksplitE arm (R10-proven 256-thr float2 form)
        int u = bid - 1280;
        int t = u % 1000, b = u / 1000;
        int c = tid * 2;
        const float2 x2 = *(const float2*)&enc[((size_t)b * TT + t) * TD + c];
        float x0 = x2.x, x1 = x2.y;
        _Float16 h0 = (_Float16)x0, h1 = (_Float16)x1;
        _Float16 l0 = (_Float16)(x0 - (float)h0), l1 = (_Float16)(x1 - (float)h1);
        int ic = c >> 5, pos = c & 31;
        size_t base = ((size_t)(b * 16 + ic) * EROWS + 1 + t) * BSTR + pos;
        half2t hh; hh[0] = h0; hh[1] = h1;
        half2t ll; ll[0] = l0; ll[1] = l1;
        *(half2t*)&encs[base] = hh;
        *(half2t*)&encs[base + 32] = ll;
    }
}

// ---------------- fused weight prep: kv + ksplitW + kc2 (path A) ----------------
// MUST launch after kprepA (see WS_CWS_BYTES hazard note).
#define WV_BLOCKS (TD + TD + 1)
__global__ __launch_bounds__(64) void kwv(const float* __restrict__ up_w, const float* __restrict__ w2,
                                          const float* __restrict__ cw,
                                          const float* __restrict__ up_b, const float* __restrict__ b2,
                                          float* __restrict__ vmat, _Float16* __restrict__ cws,
                                          float* __restrict__ c2out) {
    int bid = blockIdx.x, lane = threadIdx.x;
    if (bid < TD) {  // kv arm
        int i = bid;
        float s0 = 0, s1 = 0, s2 = 0, s3 = 0, s4 = 0;
        for (int o = lane; o < TD; o += 64) {
            float w = w2[o];
            const float* p = up_w + (size_t)i * (TD * TU) + o * TU;
            s0 += p[0] * w; s1 += p[1] * w; s2 += p[2] * w; s3 += p[3] * w; s4 += p[4] * w;
        }
#pragma unroll
        for (int m = 1; m < 64; m <<= 1) {
            s0 += __shfl_xor(s0, m); s1 += __shfl_xor(s1, m); s2 += __shfl_xor(s2, m);
            s3 += __shfl_xor(s3, m); s4 += __shfl_xor(s4, m);
        }
        if (lane == 0) {
            float* d = vmat + i * TU;
            d[0] = s0; d[1] = s1; d[2] = s2; d[3] = s3; d[4] = s4;
        }
    } else if (bid < 2 * TD) {  // ksplitW arm
        int o = bid - TD;
        for (int u = lane; u < 16 * 32 * 3; u += 64) {
            int tap = u % 3, pos = (u / 3) % 32, ic = u / 96;
            float x = cw[((size_t)o * TD + ic * 32 + pos) * 3 + tap];
            _Float16 h = (_Float16)x;
            _Float16 l = (_Float16)(x - (float)h);
            size_t base = (((size_t)(o >> 5) * 16 + ic) * 32 + (o & 31)) * ASTR + tap * 64;
            cws[base + pos] = h;
            cws[base + 32 + pos] = l;
        }
    } else {  // kc2 arm (64-lane reduction; c2 <=1 ulp shift, feeds smooth sigmoid paths only)
        float p = 0.f;
        for (int o = lane; o < TD; o += 64) p += up_b[o] * w2[o];
#pragma unroll
        for (int m = 1; m < 64; m <<= 1) p += __shfl_xor(p, m);
        if (lane == 0) c2out[0] = b2[0] + p;
    }
}

// ---------------- conv1d via fp16x3-split MFMA, DMA-staged (path A) ----------------
// EXACT R1/R8/R10 kernel (hardware-proven: 152.0 us, absmax 4.03125).
// Block: 64 o x 256 t, 4 waves, 2 blocks/CU (62.9 KB static LDS) = 8 waves/CU.
// Session findings (do not revisit):
//  - waves/CU is the binding knob: 8 beats 12 (reuse) and 4 (no cross-wave overlap).
//  - ~77us above the 74.5us MFMA floor is per-round vmcnt(0)-drain+barrier serialization;
//    dbuf escape needs 2x LDS which exceeds 160KB at any 8-wave tile.
//  - R11 (256-o, halved B re-reads, -25% LDS reads) was FLAT -> traffic not binding.
//  - fp16-split product-dropping ruled out (CIF fire-flip risk).
__global__ __launch_bounds__(256, 2) void kconvMD(const _Float16* __restrict__ encs,
                                                  const _Float16* __restrict__ cws,
                                                  const float* __restrict__ cb, const float* __restrict__ w1,
                                                  const float* __restrict__ vmat,
                                                  float* __restrict__ araw1, float* __restrict__ araw2) {
    __shared__ _Float16 sB[258 * BSTR];  // 37.1 KB; LDS row s = data t = t0-1+s
    __shared__ _Float16 sA[64 * ASTR];   // 25.6 KB (two 32-o groups)

    const int tid = threadIdx.x;
    const int t0 = blockIdx.x * 256;
    const int oc = blockIdx.y;           // 0..7, 64 outputs each
    const int b = blockIdx.z;
    const int o0 = oc * 64;
    const int wv = tid >> 6, lane = tid & 63;
    const int q = lane >> 4, l15 = lane & 15;

    float4t acc[4][4];
#pragma unroll
    for (int i = 0; i < 4; ++i)
#pragma unroll
        for (int j = 0; j < 4; ++j) acc[i][j] = (float4t){0.f, 0.f, 0.f, 0.f};

    for (int ic = 0; ic < 16; ++ic) {
        __syncthreads();
        // B tile: 258 rows x 144 B, contiguous in encs (front pad row makes t0-1 legal)
        const _Float16* gB = encs + ((size_t)(b * 16 + ic) * EROWS + t0) * BSTR;
        for (int c = tid; c < 2322; c += 256) GLOAD_LDS(gB + c * 8, &sB[c * 8]);
        // A tile: two 32-o groups, each 32 rows x 400 B contiguous
        const _Float16* gA0 = cws + ((size_t)((oc * 2 + 0) * 16 + ic) * 32) * ASTR;
        const _Float16* gA1 = cws + ((size_t)((oc * 2 + 1) * 16 + ic) * 32) * ASTR;
        for (int c = tid; c < 800; c += 256) GLOAD_LDS(gA0 + c * 8, &sA[c * 8]);
        for (int c = tid; c < 800; c += 256) GLOAD_LDS(gA1 + c * 8, &sA[6400 + c * 8]);
        __syncthreads();
        // ---- MFMA: 3 taps x 4 ot x 4 tt x 3 products ----
#pragma unroll
        for (int tap = 0; tap < 3; ++tap) {
            half8 Bh[4], Bl[4];
#pragma unroll
            for (int tt = 0; tt < 4; ++tt) {
                int s = wv * 64 + tt * 16 + l15 + tap;
                Bh[tt] = *(const half8*)&sB[s * BSTR + q * 8];
                Bl[tt] = *(const half8*)&sB[s * BSTR + 32 + q * 8];
            }
#pragma unroll
            for (int ot = 0; ot < 4; ++ot) {
                const int orow = ot * 16 + l15;
                half8 Ah = *(const half8*)&sA[orow * ASTR + tap * 64 + q * 8];
                half8 Al = *(const half8*)&sA[orow * ASTR + tap * 64 + 32 + q * 8];
#pragma unroll
                for (int tt = 0; tt < 4; ++tt) {
                    acc[ot][tt] = __builtin_amdgcn_mfma_f32_16x16x32_f16(Ah, Bh[tt], acc[ot][tt], 0, 0, 0);
                    acc[ot][tt] = __builtin_amdgcn_mfma_f32_16x16x32_f16(Ah, Bl[tt], acc[ot][tt], 0, 0, 0);
                    acc[ot][tt] = __builtin_amdgcn_mfma_f32_16x16x32_f16(Al, Bh[tt], acc[ot][tt], 0, 0, 0);
                }
            }
        }
    }

    // ---- epilogue: r=relu(conv+cb); 6 dots; quad reduce; atomics ----
#pragma unroll
    for (int tt = 0; tt < 4; ++tt) {
        int t = t0 + wv * 64 + tt * 16 + l15;
        float s1 = 0.f, sa = 0.f, sb = 0.f, sc = 0.f, sd = 0.f, se = 0.f;
#pragma unroll
        for (int ot = 0; ot < 4; ++ot) {
#pragma unroll
            for (int r = 0; r < 4; ++r) {
                int o = o0 + ot * 16 + q * 4 + r;
                float rv = fmaxf(acc[ot][tt][r] + cb[o], 0.f);
                s1 = fmaf(w1[o], rv, s1);
                const float* vp = &vmat[o * 5];
                sa = fmaf(vp[0], rv, sa); sb = fmaf(vp[1], rv, sb);
                sc = fmaf(vp[2], rv, sc); sd = fmaf(vp[3], rv, sd);
                se = fmaf(vp[4], rv, se);
            }
        }
        s1 += __shfl_xor(s1, 16); sa += __shfl_xor(sa, 16); sb += __shfl_xor(sb, 16);
        sc += __shfl_xor(sc, 16); sd += __shfl_xor(sd, 16); se += __shfl_xor(se, 16);
        s1 += __shfl_xor(s1, 32); sa += __shfl_xor(sa, 32); sb += __shfl_xor(sb, 32);
        sc += __shfl_xor(sc, 32); sd += __shfl_xor(sd, 32); se += __shfl_xor(se, 32);
        if (q == 0 && t < TT) {
            atomicAdd(&araw1[b * TT + t], s1);
            float* p2 = &araw2[(b * TT + t) * 5];
            atomicAdd(p2 + 0, sa); atomicAdd(p2 + 1, sb); atomicAdd(p2 + 2, sc);
            atomicAdd(p2 + 3, sd); atomicAdd(p2 + 4, se);
        }
    }
}

// ---------------- conv1d fallback (round-5 kernel, path B) ----------------
__global__ __launch_bounds__(256, 3) void kconvM(const float* __restrict__ enc, const float* __restrict__ cw,
                                                 const float* __restrict__ cb, const float* __restrict__ w1,
                                                 const float* __restrict__ vmat,
                                                 float* __restrict__ araw1, float* __restrict__ araw2) {
    __shared__ _Float16 sB[258 * BSTR];
    __shared__ _Float16 sA[32 * ASTR];

    const int tid = threadIdx.x;
    const int t0 = blockIdx.x * 256;
    const int o0 = blockIdx.y * 32;
    const int b = blockIdx.z;
    const int wv = tid >> 6, lane = tid & 63;
    const int q = lane >> 4, l15 = lane & 15;

    float4t acc[2][4];
#pragma unroll
    for (int i = 0; i < 2; ++i)
#pragma unroll
        for (int j = 0; j < 4; ++j) acc[i][j] = (float4t){0.f, 0.f, 0.f, 0.f};

    for (int i0 = 0; i0 < TD; i0 += 32) {
        __syncthreads();
        for (int u = tid; u < 258 * 16; u += 256) {
            int s = u >> 4, ii2 = (u & 15) << 1;
            int t = t0 - 1 + s;
            float x0 = 0.f, x1 = 0.f;
            if (t >= 0 && t < TT) {
                const float* p = &enc[((size_t)b * TT + t) * TD + i0 + ii2];
                x0 = p[0]; x1 = p[1];
            }
            _Float16 h0 = (_Float16)x0, h1 = (_Float16)x1;
            _Float16 l0 = (_Float16)(x0 - (float)h0), l1 = (_Float16)(x1 - (float)h1);
            half2t hh; hh[0] = h0; hh[1] = h1;
            half2t ll; ll[0] = l0; ll[1] = l1;
            *(half2t*)&sB[s * BSTR + ii2] = hh;
            *(half2t*)&sB[s * BSTR + 32 + ii2] = ll;
        }
        for (int u = tid; u < 32 * 16; u += 256) {
            int o = u >> 4, ii2 = (u & 15) << 1;
            const float* p = &cw[((size_t)(o0 + o) * TD + i0 + ii2) * 3];
#pragma unroll
            for (int k = 0; k < 3; ++k) {
                float x0 = p[k], x1 = p[3 + k];
                _Float16 h0 = (_Float16)x0, h1 = (_Float16)x1;
                _Float16 l0 = (_Float16)(x0 - (float)h0), l1 = (_Float16)(x1 - (float)h1);
                half2t hh; hh[0] = h0; hh[1] = h1;
                half2t ll; ll[0] = l0; ll[1] = l1;
                *(half2t*)&sA[o * ASTR + k * 64 + ii2] = hh;
                *(half2t*)&sA[o * ASTR + k * 64 + 32 + ii2] = ll;
            }
        }
        __syncthreads();
#pragma unroll
        for (int tap = 0; tap < 3; ++tap) {
            half8 Bh[4], Bl[4];
#pragma unroll
            for (int tt = 0; tt < 4; ++tt) {
                int s = wv * 64 + tt * 16 + l15 + tap;
                Bh[tt] = *(const half8*)&sB[s * BSTR + q * 8];
                Bl[tt] = *(const half8*)&sB[s * BSTR + 32 + q * 8];
            }
#pragma unroll
            for (int ot = 0; ot < 2; ++ot) {
                const int orow = ot * 16 + l15;
                half8 Ah = *(const half8*)&sA[orow * ASTR + tap * 64 + q * 8];
                half8 Al = *(const half8*)&sA[orow * ASTR + tap * 64 + 32 + q * 8];
#pragma unroll
                for (int tt = 0; tt < 4; ++tt) {
                    acc[ot][tt] = __builtin_amdgcn_mfma_f32_16x16x32_f16(Ah, Bh[tt], acc[ot][tt], 0, 0, 0);
                    acc[ot][tt] = __builtin_amdgcn_mfma_f32_16x16x32_f16(Ah, Bl[tt], acc[ot][tt], 0, 0, 0);
                    acc[ot][tt] = __builtin_amdgcn_mfma_f32_16x16x32_f16(Al, Bh[tt], acc[ot][tt], 0, 0, 0);
                }
            }
        }
    }

#pragma unroll
    for (int tt = 0; tt < 4; ++tt) {
        int t = t0 + wv * 64 + tt * 16 + l15;
        float s1 = 0.f, sa = 0.f, sb = 0.f, sc = 0.f, sd = 0.f, se = 0.f;
#pragma unroll
        for (int ot = 0; ot < 2; ++ot) {
#pragma unroll
            for (int r = 0; r < 4; ++r) {
                int o = o0 + ot * 16 + q * 4 + r;
                float rv = fmaxf(acc[ot][tt][r] + cb[o], 0.f);
                s1 = fmaf(w1[o], rv, s1);
                const float* vp = &vmat[o * 5];
                sa = fmaf(vp[0], rv, sa); sb = fmaf(vp[1], rv, sb);
                sc = fmaf(vp[2], rv, sc); sd = fmaf(vp[3], rv, sd);
                se = fmaf(vp[4], rv, se);
            }
        }
        s1 += __shfl_xor(s1, 16); sa += __shfl_xor(sa, 16); sb += __shfl_xor(sb, 16);
        sc += __shfl_xor(sc, 16); sd += __shfl_xor(sd, 16); se += __shfl_xor(se, 16);
        s1 += __shfl_xor(s1, 32); sa += __shfl_xor(sa, 32); sb += __shfl_xor(sb, 32);
        sc += __shfl_xor(sc, 32); sd += __shfl_xor(sd, 32); se += __shfl_xor(se, 32);
        if (q == 0 && t < TT) {
            atomicAdd(&araw1[b * TT + t], s1);
            float* p2 = &araw2[(b * TT + t) * 5];
            atomicAdd(p2 + 0, sa); atomicAdd(p2 + 1, sb); atomicAdd(p2 + 2, sc);
            atomicAdd(p2 + 3, sd); atomicAdd(p2 + 4, se);
        }
    }
}

// ---------------- fused alphas + sequential CIF scan ----------------
#define STEP(j, aj) { \
    float dist = 1.f - integ; \
    integ += (aj); \
    sp[tq + (j)] = integ; \
    bool fire = integ >= 1.f; \
    float cur = fire ? dist : (aj); \
    swa[tq + (j)] = cur; \
    swb[tq + (j)] = fire ? ((aj) - cur) : 0.f; \
    if (fire) { sf[F++] = tq + (j); integ -= 1.f; } \
    Ssum += (aj); }

__global__ __launch_bounds__(64) void kscan(const float* __restrict__ araw1, const float* __restrict__ araw2,
                                            const float* __restrict__ mask, const float* __restrict__ b1,
                                            const float* __restrict__ c2,
                                            float* __restrict__ alphas_t,
                                            float* __restrict__ cif_peak, float* __restrict__ token_num,
                                            float* __restrict__ tok2,
                                            float* __restrict__ wA, float* __restrict__ wB,
                                            int* __restrict__ fire_time, int* __restrict__ n_fires) {
    __shared__ float sa[TT1 + 7], sp[TT1], swa[TT1], swb[TT1];
    __shared__ int sf[TT1];
    __shared__ int sFs;
    int b = blockIdx.x, lane = threadIdx.x;

    // ---- phase 1: alphas (old kalpha, same scalar expressions) ----
    const float cc = c2[0];
    const float b1v = b1[0];
    float sum5 = 0.f;
    for (int t = lane; t < TT1 + 7; t += 64) {
        float av = 0.f;
        if (t < TT) {
            float mk = mask[b * TT + t];
            float a1 = araw1[b * TT + t] + b1v;
            float alpha = mk / (1.f + expf(-a1));
            float mprev = (t == 0) ? 1.f : mask[b * TT + t - 1];
            float tail = (mprev - mk) * 0.45f;
            av = alpha + tail;
            float x0 = araw2[(b * TT + t) * 5 + 0] + cc;
            float x1 = araw2[(b * TT + t) * 5 + 1] + cc;
            float x2 = araw2[(b * TT + t) * 5 + 2] + cc;
            float x3 = araw2[(b * TT + t) * 5 + 3] + cc;
            float x4 = araw2[(b * TT + t) * 5 + 4] + cc;
            sum5 += mk / (1.f + expf(-x0)) + mk / (1.f + expf(-x1)) + mk / (1.f + expf(-x2))
                  + mk / (1.f + expf(-x3)) + mk / (1.f + expf(-x4));
        } else if (t == TT) {
            av = mask[b * TT + TT - 1] * 0.45f;
        }
        sa[t] = (t < TT1) ? av : 0.f;
        if (t < TT1) alphas_t[b * TT1 + t] = av;
    }
#pragma unroll
    for (int m = 1; m < 64; m <<= 1) sum5 += __shfl_xor(sum5, m);
    if (lane == 0) tok2[b] = sum5;
    __syncthreads();

    // ---- phase 2: serial scan (unchanged) ----
    if (lane == 0) {
        float integ = 0.f, Ssum = 0.f;
        int F = 0;
        for (int tq = 0; tq < TT1 - 1; tq += 8) {  // 125 full chunks of 8 -> t=0..999
            float a0 = sa[tq], a1 = sa[tq + 1], a2 = sa[tq + 2], a3 = sa[tq + 3];
            float a4 = sa[tq + 4], a5 = sa[tq + 5], a6 = sa[tq + 6], a7 = sa[tq + 7];
            STEP(0, a0) STEP(1, a1) STEP(2, a2) STEP(3, a3)
            STEP(4, a4) STEP(5, a5) STEP(6, a6) STEP(7, a7)
        }
        { int tq = TT1 - 1; float a0 = sa[tq]; STEP(0, a0) }  // t = 1000
        token_num[b] = floorf(Ssum);
        n_fires[b] = F;
        sFs = F;
    }
    __syncthreads();
    int F = sFs;
    for (int t = lane; t < TT1; t += 64) {
        cif_peak[b * TT1 + t] = sp[t];
        wA[b * TT1 + t] = swa[t];
        wB[b * TT1 + t] = swb[t];
        if (t < F) fire_time[b * TT1 + t] = sf[t];
    }
}

// ---------------- gather: acoustic[b,k,:] = segmented weighted sum of encoder rows ----------------
__global__ __launch_bounds__(128) void kgather(const float* __restrict__ enc,
                                               const float* __restrict__ wA, const float* __restrict__ wB,
                                               const int* __restrict__ fire_time, const int* __restrict__ n_fires,
                                               float* __restrict__ acoustic) {
    int k = blockIdx.x, b = blockIdx.y;
    int d4 = threadIdx.x;
    float ox = 0.f, oy = 0.f, oz = 0.f, ow = 0.f;
    int nf = n_fires[b];
    if (k < nf) {
        int end = fire_time[b * TT1 + k];
        int start = (k > 0) ? fire_time[b * TT1 + k - 1] : 0;
        for (int t = start; t <= end; ++t) {
            if (t >= TT) continue;
            float w = (k > 0 && t == start) ? wB[b * TT1 + t] : wA[b * TT1 + t];
            float4 h = ((const float4*)(enc + ((size_t)b * TT + t) * TD))[d4];
            ox += w * h.x; oy += w * h.y; oz += w * h.z; ow += w * h.w;
        }
    }
    float4 o4; o4.x = ox; o4.y = oy; o4.z = oz; o4.w = ow;
    ((float4*)(acoustic + ((size_t)b * TT1 + k) * TD))[d4] = o4;
}

extern "C" void kernel_launch(void* const* d_in, const int* in_sizes, int n_in,
                              void* d_out, int out_size, void* d_ws, size_t ws_size,
                              hipStream_t stream) {
    (void)in_sizes; (void)n_in; (void)out_size;
    const float* enc = (const float*)d_in[0];
    const float* mask = (const float*)d_in[1];
    const float* cw = (const float*)d_in[2];
    const float* cb = (const float*)d_in[3];
    const float* upw = (const float*)d_in[4];
    const float* upb = (const float*)d_in[5];
    const float* w1 = (const float*)d_in[6];
    const float* b1 = (const float*)d_in[7];
    const float* w2 = (const float*)d_in[8];
    const float* b2 = (const float*)d_in[9];

    float* out = (float*)d_out;
    float* acoustic = out + OFF_ACC;
    float* token_num = out + OFF_TOKN;
    float* alphas_t = out + OFF_ALPH;
    float* cif_peak = out + OFF_PEAK;
    float* tok2 = out + OFF_TOK2;

    float* ws = (float*)d_ws;
    float* araw1 = ws + WS_ARAW1;
    float* araw2 = ws + WS_ARAW2;
    float* vmat = ws + WS_VMAT;
    float* c2 = ws + WS_C2;
    float* wA = ws + WS_WA;
    float* wB = ws + WS_WB;
    int* fire_time = (int*)(ws + WS_FIRE);
    int* n_fires = (int*)(ws + WS_NF);
    _Float16* encs = (_Float16*)((char*)d_ws + WS_ENCS_BYTES);
    _Float16* cws = (_Float16*)((char*)d_ws + WS_CWS_BYTES);

    const bool bigws = (ws_size >= WS_NEED_BYTES);  // constant across calls -> graph-safe

    if (bigws) {
        // ORDER MATTERS: kprepA (all encs writers) must precede kwv (cws writer)
        // because cws aliases the encs tail — see WS_CWS_BYTES note.
        hipLaunchKernelGGL(kprepA, dim3(PREPA_BLOCKS), dim3(256), 0, stream,
                           enc, araw1, araw2, tok2, encs);
        hipLaunchKernelGGL(kwv, dim3(WV_BLOCKS), dim3(64), 0, stream, upw, w2, cw, upb, b2, vmat, cws, c2);
        hipLaunchKernelGGL(kconvMD, dim3(4, 8, TB), dim3(256), 0, stream, encs, cws, cb, w1, vmat, araw1, araw2);
    } else {
        hipLaunchKernelGGL(kzero, dim3(256), dim3(256), 0, stream, araw1, araw2, tok2);
        hipLaunchKernelGGL(kc2, dim3(1), dim3(256), 0, stream, upb, w2, b2, c2);
        hipLaunchKernelGGL(kv, dim3(TD), dim3(64), 0, stream, upw, w2, vmat);
        hipLaunchKernelGGL(kconvM, dim3(4, 16, TB), dim3(256), 0, stream, enc, cw, cb, w1, vmat, araw1, araw2);
    }
    hipLaunchKernelGGL(kscan, dim3(TB), dim3(64), 0, stream, araw1, araw2, mask, b1, c2,
                       alphas_t, cif_peak, token_num, tok2, wA, wB, fire_time, n_fires);
    hipLaunchKernelGGL(kgather, dim3(TT1, TB), dim3(128), 0, stream, enc, wA, wB, fire_time, n_fires, acoustic);
}